// Round 18
// baseline (195.266 us; speedup 1.0000x reference)
//
#include <hip/hip_runtime.h>
#include <math.h>

// Problem constants (B=2, L=2048, D=512)
#define BB 2
#define LL 2048
#define DD 512
#define DIN 1024          // D_INNER
#define DXZ 2048          // 2*D_INNER
#define DSTATE 16
#define DTRANK 32
#define NDBL 64           // DT_RANK + 2*D_STATE
#define ML (BB*LL)        // 4096 rows
#define LC3 32            // scan chunk length
#define NCH3 64           // chunks per sequence
#define CP4 34            // padded LDS chunk stride (26.1KB, proven v19)
#define PHS 17            // Pc/Hc padded stride

typedef __bf16 bf16_t;
typedef bf16_t bf16x8 __attribute__((ext_vector_type(8)));
typedef bf16_t bf16x4 __attribute__((ext_vector_type(4)));
typedef float f32x4 __attribute__((ext_vector_type(4)));

#define GBK 64            // MFMA K-step (v14 config — best measured)

typedef const __attribute__((address_space(1))) void* gp1_t;
typedef __attribute__((address_space(3))) void* lp3_t;

__device__ __forceinline__ float fast_silu(float x) {
  return x * __builtin_amdgcn_rcpf(1.f + __builtin_amdgcn_exp2f(-1.44269504f * x));
}

// ---------------------------------------------------------------------------
// bf16 MFMA GEMM: C[M,N](f32) = A[M,K](bf16) * Bt[N,K](bf16)^T
// v14 pipeline (counted-vmcnt depth-2, GBK=64, coalesced CT=1 LDS-bounce).
// v21: gemm1/gemm6 move to TM=TN=64 tiles -> 4x/2x more blocks/CU
// (gemm1 512->2048, gemm6 256->512); operand re-reads are L2-resident.
// CT=1 epilogue generalized: TM=128 two-chunk path, TM=64 single-tile path.
// ---------------------------------------------------------------------------
template <int TM, int TN, int MODE, int CT>
__launch_bounds__(256)
__global__ void gemm_mfma(const bf16_t* __restrict__ A,
                          const bf16_t* __restrict__ Bt,
                          float* __restrict__ C, int ldc,
                          int M, int N, int K, int gx,
                          const float* __restrict__ aux) {
  constexpr int ABYTES = 2 * TM * GBK * 2;
  constexpr int BBYTES = 2 * TN * GBK * 2;
  constexpr int TBYTES = 64 * 68 * 4;
  constexpr int SBYTES = (CT == 1 && ABYTES + BBYTES < TBYTES)
                             ? TBYTES : ABYTES + BBYTES;
  __shared__ __align__(16) char smem[SBYTES];
  bf16_t* As = (bf16_t*)smem;                 // [2][TM*GBK]
  bf16_t* Bs = (bf16_t*)(smem + ABYTES);      // [2][TN*GBK]
  const int tid = threadIdx.x;
  const int wid = tid >> 6, lane = tid & 63;
  const int q = lane >> 4, ln = lane & 15;
  constexpr int WM = TM / 2, WN = TN / 2;
  constexpr int FM = WM / 16, FN = WN / 16;
  constexpr int AI = TM * GBK / 2048;   // A-stage instrs per wave (8 rows each)
  constexpr int BI = TN * GBK / 2048;   // B-stage instrs per wave
  constexpr int SN = AI + BI;           // per-wave loads per stage
  const int wm = (wid >> 1) * WM, wn = (wid & 1) * WN;

  const int nwg = gridDim.x;
  const int cpx = nwg >> 3;
  const int o = blockIdx.x;
  const int wg = (o & 7) * cpx + (o >> 3);
  const int bx = wg % gx, by = wg / gx;

  const int mBase = by * TM, nBase = bx * TN;
  const int lr = lane >> 3, lk = (lane & 7) * 8;   // 8 rows x 64B per instr

  auto stage = [&](int buf, int k0) {
#pragma unroll
    for (int t = 0; t < AI; t++) {
      const int grp = wid * AI + t;
      const bf16_t* g = &A[(size_t)(mBase + grp * 8 + lr) * K + k0 + lk];
      __builtin_amdgcn_global_load_lds((gp1_t)(const void*)g,
                                       (lp3_t)(void*)&As[buf * TM * GBK + grp * 512],
                                       16, 0, 0);
    }
#pragma unroll
    for (int t = 0; t < BI; t++) {
      const int grp = wid * BI + t;
      const bf16_t* g = &Bt[(size_t)(nBase + grp * 8 + lr) * K + k0 + lk];
      __builtin_amdgcn_global_load_lds((gp1_t)(const void*)g,
                                       (lp3_t)(void*)&Bs[buf * TN * GBK + grp * 512],
                                       16, 0, 0);
    }
  };

  f32x4 acc[FM][FN] = {};
  const int NK = K / GBK;
  stage(0, 0);
  stage(1, GBK);                       // depth-2 prologue (NK>=2 always here)
  for (int t = 0; t < NK; t++) {
    const int cur = t & 1;
    // Wait for CURRENT buffer's loads only; the newest SN (next tile) fly on.
    if (t < NK - 1) {
      if constexpr (SN == 8)      asm volatile("s_waitcnt vmcnt(8)" ::: "memory");
      else if constexpr (SN == 6) asm volatile("s_waitcnt vmcnt(6)" ::: "memory");
      else if constexpr (SN == 4) asm volatile("s_waitcnt vmcnt(4)" ::: "memory");
      else                        asm volatile("s_waitcnt vmcnt(0)" ::: "memory");
    } else {
      asm volatile("s_waitcnt vmcnt(0)" ::: "memory");
    }
    __builtin_amdgcn_s_barrier();
    __builtin_amdgcn_sched_barrier(0);   // no ds_read hoisted above barrier
    bf16x8 af[FM][2], bfr[FN][2];
#pragma unroll
    for (int i = 0; i < FM; i++)
#pragma unroll
      for (int h = 0; h < 2; h++)
        af[i][h] = *(const bf16x8*)
            &As[cur * TM * GBK + (wm + i * 16 + ln) * GBK + h * 32 + q * 8];
#pragma unroll
    for (int j = 0; j < FN; j++)
#pragma unroll
      for (int h = 0; h < 2; h++)
        bfr[j][h] = *(const bf16x8*)
            &Bs[cur * TN * GBK + (wn + j * 16 + ln) * GBK + h * 32 + q * 8];
#pragma unroll
    for (int i = 0; i < FM; i++)
#pragma unroll
      for (int j = 0; j < FN; j++) {
        acc[i][j] = __builtin_amdgcn_mfma_f32_16x16x32_bf16(
            af[i][0], bfr[j][0], acc[i][j], 0, 0, 0);
        acc[i][j] = __builtin_amdgcn_mfma_f32_16x16x32_bf16(
            af[i][1], bfr[j][1], acc[i][j], 0, 0, 0);
      }
    __builtin_amdgcn_s_barrier();        // all waves done reading cur
    __builtin_amdgcn_sched_barrier(0);   // no stage sunk above this barrier
    if (t + 2 < NK) stage(cur, (t + 2) * GBK);
  }

  if constexpr (CT == 1 && TM == 128) {
    // Two-chunk coalesced transposed store (TM=TN=128).
    float (*T)[68] = (float(*)[68])smem;
#pragma unroll
    for (int ch = 0; ch < 2; ch++) {
      __syncthreads();
      if ((wid & 1) == ch) {
#pragma unroll
        for (int i = 0; i < FM; i++)
#pragma unroll
          for (int j = 0; j < FN; j++)
            *(f32x4*)&T[j * 16 + ln][wm + i * 16 + q * 4] = acc[i][j];
      }
      __syncthreads();
#pragma unroll
      for (int it = 0; it < 8; it++) {
        const int idx = tid + it * 256;
        const int row = idx >> 5, off = (idx & 31) * 4;
        *(f32x4*)&C[(size_t)(nBase + ch * 64 + row) * ldc + mBase + off] =
            *(const f32x4*)&T[row][off];
      }
    }
  } else if constexpr (CT == 1) {
    // Single-tile coalesced transposed store (TM=TN=64): all 4 waves write
    // disjoint cells of one 64x68 tile, then flush 64 rows x 256B.
    float (*T)[68] = (float(*)[68])smem;
    __syncthreads();
#pragma unroll
    for (int i = 0; i < FM; i++)
#pragma unroll
      for (int j = 0; j < FN; j++)
        *(f32x4*)&T[wn + j * 16 + ln][wm + i * 16 + q * 4] = acc[i][j];
    __syncthreads();
#pragma unroll
    for (int it = 0; it < 4; it++) {
      const int idx = tid + it * 256;
      const int row = idx >> 4, off = (idx & 15) * 4;
      *(f32x4*)&C[(size_t)(nBase + row) * ldc + mBase + off] =
          *(const f32x4*)&T[row][off];
    }
  } else {
#pragma unroll
    for (int i = 0; i < FM; i++) {
      const int m0 = mBase + wm + i * 16 + q * 4;
#pragma unroll
      for (int j = 0; j < FN; j++) {
        const int n = nBase + wn + j * 16 + ln;
#pragma unroll
        for (int r = 0; r < 4; r++) {
          float v = acc[i][j][r];
          if (MODE == 2) v += aux[(size_t)(m0 + r) * ldc + n];
          C[(size_t)(m0 + r) * ldc + n] = v;
        }
      }
    }
  }
}

// ---------------------------------------------------------------------------
// Fused prep: x cast (blocks 0..2047) + W_in/W_x/W_out transpose-casts.
// ---------------------------------------------------------------------------
__launch_bounds__(256)
__global__ void prep(const float* __restrict__ x, bf16_t* __restrict__ x_b,
                     const float* __restrict__ W_in, bf16_t* __restrict__ W_inT_b,
                     const float* __restrict__ W_x, bf16_t* __restrict__ W_xT_b,
                     const float* __restrict__ W_out, bf16_t* __restrict__ W_outT_b) {
  __shared__ float T[64][65];
  const int blk = blockIdx.x;
  const int t = threadIdx.x;

  if (blk < 2048) {                       // cast x -> x_b (bf16)
    const int i = blk * 256 + t;
    const float4 v = ((const float4*)x)[i];
    bf16x4 o = {(bf16_t)v.x, (bf16_t)v.y, (bf16_t)v.z, (bf16_t)v.w};
    ((bf16x4*)x_b)[i] = o;
    return;
  }
  const float* in;
  bf16_t* out;
  int R, C, bx, by;
  if (blk < 2304) {                       // W_in: [512][2048] -> T
    const int k = blk - 2048;
    in = W_in; out = W_inT_b; R = DD; C = DXZ; bx = k & 31; by = k >> 5;
  } else if (blk < 2320) {                // W_x: [1024][64] -> T
    const int k = blk - 2304;
    in = W_x; out = W_xT_b; R = DIN; C = NDBL; bx = 0; by = k;
  } else {                                // W_out: [1024][512] -> T
    const int k = blk - 2320;
    in = W_out; out = W_outT_b; R = DIN; C = DD; bx = k & 7; by = k >> 3;
  }
  const int rB = by * 64, cB = bx * 64;
  {
    const int r = t >> 4, c4 = (t & 15) * 4;
#pragma unroll
    for (int i = 0; i < 4; i++) {
      const float4 v = *(const float4*)&in[(size_t)(rB + r + i * 16) * C + cB + c4];
      T[r + i * 16][c4] = v.x;
      T[r + i * 16][c4 + 1] = v.y;
      T[r + i * 16][c4 + 2] = v.z;
      T[r + i * 16][c4 + 3] = v.w;
    }
  }
  __syncthreads();
  {
    const int c = t >> 2;
#pragma unroll
    for (int i = 0; i < 4; i++) {
      const int r0 = (t & 3) * 16 + i * 4;
      bf16x4 o = {(bf16_t)T[r0][c], (bf16_t)T[r0 + 1][c],
                  (bf16_t)T[r0 + 2][c], (bf16_t)T[r0 + 3][c]};
      *(bf16x4*)&out[(size_t)(cB + c) * R + rB + r0] = o;
    }
  }
}

// ---------------------------------------------------------------------------
// bf16 tiled transpose: in bf16 [R][C] -> out bf16 [C][R]. 64x64 tiles.
// ---------------------------------------------------------------------------
__launch_bounds__(256)
__global__ void transpose_b16(const bf16_t* __restrict__ in, bf16_t* __restrict__ out,
                              int R, int C) {
  __shared__ bf16_t T[64][72];
  const int t = threadIdx.x;
  const int rB = blockIdx.y * 64, cB = blockIdx.x * 64;
  const int r = t >> 2, c16 = (t & 3) * 16;
#pragma unroll
  for (int i = 0; i < 2; i++) {
    const bf16x8 v = *(const bf16x8*)&in[(size_t)(rB + r) * C + cB + c16 + i * 8];
#pragma unroll
    for (int k = 0; k < 8; k++) T[c16 + i * 8 + k][r] = v[k];
  }
  __syncthreads();
#pragma unroll
  for (int i = 0; i < 2; i++) {
    const int cc = (t & 3) * 16 + i * 8;
    bf16x8 v;
#pragma unroll
    for (int k = 0; k < 8; k++) v[k] = T[r][cc + k];
    *(bf16x8*)&out[(size_t)(cB + r) * R + rB + cc] = v;
  }
}

// ---------------------------------------------------------------------------
// fp32 tiled GEMM (GEMM4 only): 64x64 tile, BK=16.
// MODE 1: softplus(acc+bias[n]); CT=1: transposed store via LDS bounce.
// ---------------------------------------------------------------------------
template <int MODE, int AT, int CT>
__launch_bounds__(256)
__global__ void gemm_tiled(const float* __restrict__ A, int lda,
                           const float* __restrict__ B, int ldb,
                           float* __restrict__ C, int ldc,
                           int M, int N, int K,
                           const float* __restrict__ aux) {
  __shared__ float As[16][68];
  __shared__ float Bs[16][68];

  const int tid = threadIdx.x;
  const int tx = tid & 15, ty = tid >> 4;
  const int mBase = blockIdx.y * 64;
  const int nBase = blockIdx.x * 64;

  float acc[4][4] = {};

  for (int k0 = 0; k0 < K; k0 += 16) {
#pragma unroll
    for (int i = 0; i < 4; i++) {
      int idx = tid + i * 256;
      if (AT == 0) {
        int m = idx >> 4, kk = idx & 15;
        As[kk][m] = A[(size_t)(mBase + m) * lda + k0 + kk];
      } else {
        int kk = idx >> 6, m = idx & 63;
        As[kk][m] = A[(size_t)(k0 + kk) * lda + mBase + m];
      }
    }
#pragma unroll
    for (int i = 0; i < 4; i++) {
      int idx = tid + i * 256;
      int kk = idx >> 6, n = idx & 63;
      Bs[kk][n] = B[(size_t)(k0 + kk) * ldb + nBase + n];
    }
    __syncthreads();
#pragma unroll
    for (int kk = 0; kk < 16; kk++) {
      const float4 a4 = *reinterpret_cast<const float4*>(&As[kk][ty * 4]);
      const float4 b4 = *reinterpret_cast<const float4*>(&Bs[kk][tx * 4]);
      const float a[4] = {a4.x, a4.y, a4.z, a4.w};
      const float b[4] = {b4.x, b4.y, b4.z, b4.w};
#pragma unroll
      for (int i = 0; i < 4; i++)
#pragma unroll
        for (int j = 0; j < 4; j++) acc[i][j] = fmaf(a[i], b[j], acc[i][j]);
    }
    __syncthreads();
  }

  if (CT == 0) {
#pragma unroll
    for (int i = 0; i < 4; i++) {
      const int m = mBase + ty * 4 + i;
      const int n0 = nBase + tx * 4;
      float v[4];
#pragma unroll
      for (int j = 0; j < 4; j++) {
        float x = acc[i][j];
        if (MODE == 1) {
          x += aux[n0 + j];
          x = (x > 20.f) ? x
              : 0.69314718f * __builtin_amdgcn_logf(
                    1.f + __builtin_amdgcn_exp2f(x * 1.44269504f));
        }
        v[j] = x;
      }
      *reinterpret_cast<float4*>(&C[(size_t)m * ldc + n0]) =
          make_float4(v[0], v[1], v[2], v[3]);
    }
  } else {
    // Transposed store via LDS bounce: rows n, 256B contiguous m-segments.
    __shared__ float T3[64][68];
#pragma unroll
    for (int i = 0; i < 4; i++)
#pragma unroll
      for (int j = 0; j < 4; j++) {
        float x = acc[i][j];
        if (MODE == 1) {
          x += aux[nBase + tx * 4 + j];
          x = (x > 20.f) ? x
              : 0.69314718f * __builtin_amdgcn_logf(
                    1.f + __builtin_amdgcn_exp2f(x * 1.44269504f));
        }
        T3[tx * 4 + j][ty * 4 + i] = x;
      }
    __syncthreads();
#pragma unroll
    for (int it = 0; it < 4; it++) {
      const int idx = tid + it * 256;
      const int row = idx >> 4, off = (idx & 15) * 4;
      *(float4*)&C[(size_t)(nBase + row) * ldc + mBase + off] =
          *(const float4*)&T3[row][off];
    }
  }
}

// ---------------------------------------------------------------------------
// Fused depthwise causal conv (k=4) + bias + SiLU + transposed bf16 output.
// ---------------------------------------------------------------------------
__launch_bounds__(256)
__global__ void conv_silu_T2(const float* __restrict__ xzT,
                             const float* __restrict__ conv_w,
                             const float* __restrict__ conv_b,
                             float* __restrict__ uT,
                             bf16_t* __restrict__ u_b) {
  __shared__ bf16_t T[64][72];   // [ml_local][d_local], pad 72
  const int t = threadIdx.x;
  const int d0 = blockIdx.y * 64, ml0 = blockIdx.x * 64;
  const int dd = t >> 2;               // 0..63
  const int m4 = (t & 3) * 16;         // 0,16,32,48
  const int d = d0 + dd;
  const float* row = xzT + (size_t)d * ML + ml0 + m4;
  float* orow = uT + (size_t)d * ML + ml0 + m4;
  const float w0 = conv_w[d * 4 + 0], w1 = conv_w[d * 4 + 1];
  const float w2 = conv_w[d * 4 + 2], w3 = conv_w[d * 4 + 3];
  const float bias = conv_b[d];
  const int l0 = (ml0 + m4) & (LL - 1);
  float4 Av = make_float4(0.f, 0.f, 0.f, 0.f);
  if (l0 != 0) Av = *(const float4*)(row - 4);
#pragma unroll
  for (int j = 0; j < 4; j++) {
    const float4 Bv = *(const float4*)(row + j * 4);
    float o0 = bias + w0 * Av.y + w1 * Av.z + w2 * Av.w + w3 * Bv.x;
    float o1 = bias + w0 * Av.z + w1 * Av.w + w2 * Bv.x + w3 * Bv.y;
    float o2 = bias + w0 * Av.w + w1 * Bv.x + w2 * Bv.y + w3 * Bv.z;
    float o3 = bias + w0 * Bv.x + w1 * Bv.y + w2 * Bv.z + w3 * Bv.w;
    o0 = fast_silu(o0); o1 = fast_silu(o1);
    o2 = fast_silu(o2); o3 = fast_silu(o3);
    *(float4*)(orow + j * 4) = make_float4(o0, o1, o2, o3);
    T[m4 + j * 4 + 0][dd] = (bf16_t)o0;
    T[m4 + j * 4 + 1][dd] = (bf16_t)o1;
    T[m4 + j * 4 + 2][dd] = (bf16_t)o2;
    T[m4 + j * 4 + 3][dd] = (bf16_t)o3;
    Av = Bv;
  }
  __syncthreads();
  const int r = t >> 2;
#pragma unroll
  for (int i = 0; i < 2; i++) {
    const int cc = (t & 3) * 16 + i * 8;
    bf16x8 v;
#pragma unroll
    for (int k = 0; k < 8; k++) v[k] = T[r][cc + k];
    *(bf16x8*)&u_b[(size_t)(ml0 + r) * DIN + d0 + cc] = v;
  }
}

// ---------------------------------------------------------------------------
// Fused chunked selective scan v6f (proven 51.3us, v20): CP=34, lb(256,4),
// bf16 y epilogue into yT_b overlay.
// ---------------------------------------------------------------------------
__launch_bounds__(256, 4)
__global__ void scan_fused6f(const float* __restrict__ dtT,
                             const float* __restrict__ uT,
                             const float* __restrict__ xzT,
                             bf16_t* __restrict__ yT_b,
                             const float* __restrict__ xdbl,
                             const float* __restrict__ A_log,
                             const float* __restrict__ D_param) {
  __shared__ float dt_s[NCH3 * CP4];
  __shared__ float u_s[NCH3 * CP4];     // holds u, then y' after phase 3
  __shared__ float Pc[NCH3][PHS];       // decay products, then Hin in place
  __shared__ float Hc[NCH3][PHS];

  const int tid = threadIdx.x;
  const int c = blockIdx.x;
  const int b = c >> 10, d = c & (DIN - 1);
  const size_t rowoff = (size_t)d * ML + (size_t)b * LL;
  const float* dtrow = dtT + rowoff;
  const float* urow  = uT + rowoff;
  const float* zrow  = xzT + (size_t)(DIN + d) * ML + (size_t)b * LL;
  bf16_t* yrow = yT_b + rowoff;

  // Stage dt,u rows (2048 floats each), coalesced float4: 2 per thread.
#pragma unroll
  for (int i = 0; i < 2; i++) {
    const int idx = (tid + i * 256) * 4;
    const int la = (idx >> 5) * CP4 + (idx & 31);
    *(float4*)&dt_s[la] = *(const float4*)&dtrow[idx];
    *(float4*)&u_s[la]  = *(const float4*)&urow[idx];
  }

  const int ch = tid >> 2, q = tid & 3;
  const int s0 = q * 4;
  float Al2[4];
#pragma unroll
  for (int k = 0; k < 4; k++)
    Al2[k] = -expf(A_log[d * DSTATE + s0 + k]) * 1.44269504f;
  const float* dp = dt_s + ch * CP4;
  float* up = u_s + ch * CP4;
  const float* BC = xdbl + ((size_t)b * LL + (size_t)ch * LC3) * NDBL + DTRANK + s0;
  __syncthreads();

  // Phase 1: local scan (h0=0) -> end-state Hc and decay product Pc.
  {
    float h0 = 0.f, h1 = 0.f, h2 = 0.f, h3 = 0.f, sdt = 0.f;
    float4 Bcur[4];
#pragma unroll
    for (int i = 0; i < 4; i++)
      Bcur[i] = *(const float4*)(BC + (size_t)i * NDBL);
    for (int g = 0; g < 8; g++) {
      float4 Bnxt[4];
      // prefetch next group (g=7 reads rows past the chunk: in-ws, unused)
#pragma unroll
      for (int i = 0; i < 4; i++)
        Bnxt[i] = *(const float4*)(BC + (size_t)((g + 1) * 4 + i) * NDBL);
#pragma unroll
      for (int i = 0; i < 4; i++) {
        const int l = g * 4 + i;
        const float dtv = dp[l];
        const float dtu = dtv * up[l];
        sdt += dtv;
        const float e0 = __builtin_amdgcn_exp2f(dtv * Al2[0]);
        const float e1 = __builtin_amdgcn_exp2f(dtv * Al2[1]);
        const float e2 = __builtin_amdgcn_exp2f(dtv * Al2[2]);
        const float e3 = __builtin_amdgcn_exp2f(dtv * Al2[3]);
        h0 = fmaf(h0, e0, dtu * Bcur[i].x);
        h1 = fmaf(h1, e1, dtu * Bcur[i].y);
        h2 = fmaf(h2, e2, dtu * Bcur[i].z);
        h3 = fmaf(h3, e3, dtu * Bcur[i].w);
      }
#pragma unroll
      for (int i = 0; i < 4; i++) Bcur[i] = Bnxt[i];
    }
    Pc[ch][s0 + 0] = __builtin_amdgcn_exp2f(Al2[0] * sdt);
    Pc[ch][s0 + 1] = __builtin_amdgcn_exp2f(Al2[1] * sdt);
    Pc[ch][s0 + 2] = __builtin_amdgcn_exp2f(Al2[2] * sdt);
    Pc[ch][s0 + 3] = __builtin_amdgcn_exp2f(Al2[3] * sdt);
    Hc[ch][s0 + 0] = h0;
    Hc[ch][s0 + 1] = h1;
    Hc[ch][s0 + 2] = h2;
    Hc[ch][s0 + 3] = h3;
  }
  __syncthreads();

  // Phase 2: serial combine over 64 chunks; Hin overwrites Pc in place.
  if (tid < DSTATE) {
    float h = 0.f;
#pragma unroll
    for (int k = 0; k < NCH3; k++) {
      const float Pv = Pc[k][tid], Hv = Hc[k][tid];
      Pc[k][tid] = h;                 // Hin for chunk k
      h = fmaf(h, Pv, Hv);
    }
  }
  __syncthreads();

  // Phase 3: re-scan from Hin; write pre-gate y' into u_s (slot l is dead
  // after its same-iteration read — wave lanes are synchronous).
  {
    const float Dp = D_param[d];
    float h0 = Pc[ch][s0], h1 = Pc[ch][s0 + 1];
    float h2 = Pc[ch][s0 + 2], h3 = Pc[ch][s0 + 3];
    float4 Bcur[4], Ccur[4];
#pragma unroll
    for (int i = 0; i < 4; i++) {
      Bcur[i] = *(const float4*)(BC + (size_t)i * NDBL);
      Ccur[i] = *(const float4*)(BC + (size_t)i * NDBL + DSTATE);
    }
    for (int g = 0; g < 8; g++) {
      float4 Bnxt[4], Cnxt[4];
#pragma unroll
      for (int i = 0; i < 4; i++) {
        Bnxt[i] = *(const float4*)(BC + (size_t)((g + 1) * 4 + i) * NDBL);
        Cnxt[i] = *(const float4*)(BC + (size_t)((g + 1) * 4 + i) * NDBL + DSTATE);
      }
#pragma unroll
      for (int i = 0; i < 4; i++) {
        const int l = g * 4 + i;
        const float dtv = dp[l];
        const float uv = up[l];
        const float dtu = dtv * uv;
        const float e0 = __builtin_amdgcn_exp2f(dtv * Al2[0]);
        const float e1 = __builtin_amdgcn_exp2f(dtv * Al2[1]);
        const float e2 = __builtin_amdgcn_exp2f(dtv * Al2[2]);
        const float e3 = __builtin_amdgcn_exp2f(dtv * Al2[3]);
        h0 = fmaf(h0, e0, dtu * Bcur[i].x);
        h1 = fmaf(h1, e1, dtu * Bcur[i].y);
        h2 = fmaf(h2, e2, dtu * Bcur[i].z);
        h3 = fmaf(h3, e3, dtu * Bcur[i].w);
        float p = fmaf(h0, Ccur[i].x,
                  fmaf(h1, Ccur[i].y, fmaf(h2, Ccur[i].z, h3 * Ccur[i].w)));
        p += __int_as_float(__builtin_amdgcn_ds_swizzle(__float_as_int(p), 0x041F));
        p += __int_as_float(__builtin_amdgcn_ds_swizzle(__float_as_int(p), 0x081F));
        if (q == (l & 3)) up[l] = fmaf(uv, Dp, p);   // y' into dead u slot
      }
#pragma unroll
      for (int i = 0; i < 4; i++) { Bcur[i] = Bnxt[i]; Ccur[i] = Cnxt[i]; }
    }
  }
  __syncthreads();

  // Epilogue: coalesced gated bf16 write  y = bf16(y' * silu(z)).
#pragma unroll
  for (int i = 0; i < 2; i++) {
    const int idx = (tid + i * 256) * 4;
    const int la = (idx >> 5) * CP4 + (idx & 31);
    const float4 y4 = *(const float4*)&u_s[la];
    const float4 z4 = *(const float4*)&zrow[idx];
    bf16x4 o = {(bf16_t)(y4.x * fast_silu(z4.x)),
                (bf16_t)(y4.y * fast_silu(z4.y)),
                (bf16_t)(y4.z * fast_silu(z4.z)),
                (bf16_t)(y4.w * fast_silu(z4.w))};
    *(bf16x4*)&yrow[idx] = o;
  }
}

// ---------------------------------------------------------------------------
extern "C" void kernel_launch(void* const* d_in, const int* in_sizes, int n_in,
                              void* d_out, int out_size, void* d_ws, size_t ws_size,
                              hipStream_t stream) {
  const float* x      = (const float*)d_in[0];
  const float* W_in   = (const float*)d_in[1];
  const float* conv_w = (const float*)d_in[2];
  const float* conv_b = (const float*)d_in[3];
  const float* W_x    = (const float*)d_in[4];
  const float* W_dt   = (const float*)d_in[5];
  const float* b_dt   = (const float*)d_in[6];
  const float* A_log  = (const float*)d_in[7];
  const float* D_par  = (const float*)d_in[8];
  const float* W_out  = (const float*)d_in[9];
  float* out = (float*)d_out;

  char* ws = (char*)d_ws;
  float* xzT   = (float*)(ws);                                  // [2048][4096] 32MB
  bf16_t* yT_b = (bf16_t*)(ws);             // overlay: first 8MB of xzT (rows
                                            // 0..1023 are dead by scan time)
  float* uT    = (float*)(ws + (size_t)ML * DXZ * 4);           // [1024][4096] 16MB
  float* x_dbl = (float*)(ws + (size_t)ML * (DXZ + DIN) * 4);   // [4096][64]   1MB
  char* dtT_b  = ws + (size_t)ML * (DXZ + DIN + NDBL) * 4;
  float* dtT   = (float*)dtT_b;                                 // [1024][4096] 16MB
  bf16_t* u_b  = (bf16_t*)dtT_b;            // overlay: dead before GEMM4 writes dtT (8MB)
  bf16_t* y_b  = (bf16_t*)(dtT_b + (size_t)ML * DIN * 2);       // overlay: after scan (8MB)
  char* extra  = ws + (size_t)ML * (DXZ + DIN + NDBL + DIN) * 4;
  bf16_t* x_b      = (bf16_t*)(extra);                          // [4096][512]  4MB
  bf16_t* W_inT_b  = (bf16_t*)(extra + (size_t)ML * DD * 2);    // [2048][512]  2MB
  bf16_t* W_outT_b = (bf16_t*)(extra + (size_t)ML * DD * 2 + (size_t)DXZ * DD * 2); // [512][1024] 1MB
  bf16_t* W_xT_b   = (bf16_t*)(extra + (size_t)ML * DD * 2 + (size_t)DXZ * DD * 2
                               + (size_t)DD * DIN * 2);         // [64][1024] 128KB

  // 0) fused prep: x cast + all weight transposes (one launch)
  prep<<<2448, 256, 0, stream>>>(x, x_b, W_in, W_inT_b, W_x, W_xT_b,
                                 W_out, W_outT_b);

  // 1) xzT = (x @ W_in)^T  via bf16 MFMA, 64x64 tiles (2048 wgs = 8/CU)
  gemm_mfma<64, 64, 0, 1><<<2048, 256, 0, stream>>>(
      x_b, W_inT_b, xzT, ML, ML, DXZ, DD, 32, nullptr);

  // 2) uT = silu(causal_conv4(xzT rows 0..1023) + conv_b); also emits
  //    u_b = bf16 transpose (fused)
  conv_silu_T2<<<dim3(ML / 64, DIN / 64), 256, 0, stream>>>(
      xzT, conv_w, conv_b, uT, u_b);

  // 3) x_dbl = u @ W_x  via bf16 MFMA  (4096x1024)@(1024x64)  (64 wgs, gx=1)
  gemm_mfma<64, 64, 0, 0><<<64, 256, 0, stream>>>(
      u_b, W_xT_b, x_dbl, NDBL, ML, NDBL, DIN, 1, nullptr);

  // 4) dtT = softplus(x_dbl[:, :32] @ W_dt + b_dt)^T  (fp32, K=32),
  //    coalesced transposed store via LDS bounce
  gemm_tiled<1, 0, 1><<<dim3(DIN / 64, ML / 64), 256, 0, stream>>>(
      x_dbl, NDBL, W_dt, DIN, dtT, ML, ML, DIN, DTRANK, b_dt);

  // 5) fused chunked scan + gated bf16 epilogue -> yT_b (overlay on dead
  //    xzT rows 0..1023; z rows 1024..2047 untouched)
  scan_fused6f<<<BB * DIN, 256, 0, stream>>>(dtT, uT, xzT, yT_b, x_dbl,
                                             A_log, D_par);

  // 5b) y_b = transpose(yT_b) -> bf16 [4096][1024]
  transpose_b16<<<dim3(ML / 64, DIN / 64), 256, 0, stream>>>(yT_b, y_b, DIN, ML);

  // 6) out = x + y @ W_out  via bf16 MFMA, 64x64 tiles (512 wgs = 2/CU)
  gemm_mfma<64, 64, 2, 0><<<512, 256, 0, stream>>>(
      y_b, W_outT_b, out, DD, ML, DD, DIN, 8, x);
}

// Round 19
// 191.023 us; speedup vs baseline: 1.0222x; 1.0222x over previous
//
#include <hip/hip_runtime.h>
#include <math.h>

// Problem constants (B=2, L=2048, D=512)
#define BB 2
#define LL 2048
#define DD 512
#define DIN 1024          // D_INNER
#define DXZ 2048          // 2*D_INNER
#define DSTATE 16
#define DTRANK 32
#define NDBL 64           // DT_RANK + 2*D_STATE
#define ML (BB*LL)        // 4096 rows
#define LC3 32            // scan chunk length
#define NCH3 64           // chunks per sequence
#define CP4 34            // padded LDS chunk stride (26.1KB, proven v19)
#define PHS 17            // Pc/Hc padded stride

typedef __bf16 bf16_t;
typedef bf16_t bf16x8 __attribute__((ext_vector_type(8)));
typedef bf16_t bf16x4 __attribute__((ext_vector_type(4)));
typedef float f32x4 __attribute__((ext_vector_type(4)));

#define GBK 64            // MFMA K-step (v14 config — best measured)

typedef const __attribute__((address_space(1))) void* gp1_t;
typedef __attribute__((address_space(3))) void* lp3_t;

__device__ __forceinline__ float fast_silu(float x) {
  return x * __builtin_amdgcn_rcpf(1.f + __builtin_amdgcn_exp2f(-1.44269504f * x));
}

// ---------------------------------------------------------------------------
// bf16 MFMA GEMM: C[M,N](f32) = A[M,K](bf16) * Bt[N,K](bf16)^T
// v14/v20 config (best measured): counted-vmcnt depth-2 pipeline, GBK=64,
// coalesced CT=1 epilogue via LDS bounce. CT=1 only at TM=TN=128.
// ---------------------------------------------------------------------------
template <int TM, int TN, int MODE, int CT>
__launch_bounds__(256)
__global__ void gemm_mfma(const bf16_t* __restrict__ A,
                          const bf16_t* __restrict__ Bt,
                          float* __restrict__ C, int ldc,
                          int M, int N, int K, int gx,
                          const float* __restrict__ aux) {
  constexpr int ABYTES = 2 * TM * GBK * 2;
  constexpr int BBYTES = 2 * TN * GBK * 2;
  __shared__ __align__(16) char smem[ABYTES + BBYTES];
  bf16_t* As = (bf16_t*)smem;                 // [2][TM*GBK]
  bf16_t* Bs = (bf16_t*)(smem + ABYTES);      // [2][TN*GBK]
  const int tid = threadIdx.x;
  const int wid = tid >> 6, lane = tid & 63;
  const int q = lane >> 4, ln = lane & 15;
  constexpr int WM = TM / 2, WN = TN / 2;
  constexpr int FM = WM / 16, FN = WN / 16;
  constexpr int AI = TM * GBK / 2048;   // A-stage instrs per wave (8 rows each)
  constexpr int BI = TN * GBK / 2048;   // B-stage instrs per wave
  constexpr int SN = AI + BI;           // per-wave loads per stage
  const int wm = (wid >> 1) * WM, wn = (wid & 1) * WN;

  const int nwg = gridDim.x;
  const int cpx = nwg >> 3;
  const int o = blockIdx.x;
  const int wg = (o & 7) * cpx + (o >> 3);
  const int bx = wg % gx, by = wg / gx;

  const int mBase = by * TM, nBase = bx * TN;
  const int lr = lane >> 3, lk = (lane & 7) * 8;   // 8 rows x 64B per instr

  auto stage = [&](int buf, int k0) {
#pragma unroll
    for (int t = 0; t < AI; t++) {
      const int grp = wid * AI + t;
      const bf16_t* g = &A[(size_t)(mBase + grp * 8 + lr) * K + k0 + lk];
      __builtin_amdgcn_global_load_lds((gp1_t)(const void*)g,
                                       (lp3_t)(void*)&As[buf * TM * GBK + grp * 512],
                                       16, 0, 0);
    }
#pragma unroll
    for (int t = 0; t < BI; t++) {
      const int grp = wid * BI + t;
      const bf16_t* g = &Bt[(size_t)(nBase + grp * 8 + lr) * K + k0 + lk];
      __builtin_amdgcn_global_load_lds((gp1_t)(const void*)g,
                                       (lp3_t)(void*)&Bs[buf * TN * GBK + grp * 512],
                                       16, 0, 0);
    }
  };

  f32x4 acc[FM][FN] = {};
  const int NK = K / GBK;
  stage(0, 0);
  stage(1, GBK);                       // depth-2 prologue (NK>=2 always here)
  for (int t = 0; t < NK; t++) {
    const int cur = t & 1;
    // Wait for CURRENT buffer's loads only; the newest SN (next tile) fly on.
    if (t < NK - 1) {
      if constexpr (SN == 8)      asm volatile("s_waitcnt vmcnt(8)" ::: "memory");
      else if constexpr (SN == 6) asm volatile("s_waitcnt vmcnt(6)" ::: "memory");
      else if constexpr (SN == 4) asm volatile("s_waitcnt vmcnt(4)" ::: "memory");
      else                        asm volatile("s_waitcnt vmcnt(0)" ::: "memory");
    } else {
      asm volatile("s_waitcnt vmcnt(0)" ::: "memory");
    }
    __builtin_amdgcn_s_barrier();
    __builtin_amdgcn_sched_barrier(0);   // no ds_read hoisted above barrier
    bf16x8 af[FM][2], bfr[FN][2];
#pragma unroll
    for (int i = 0; i < FM; i++)
#pragma unroll
      for (int h = 0; h < 2; h++)
        af[i][h] = *(const bf16x8*)
            &As[cur * TM * GBK + (wm + i * 16 + ln) * GBK + h * 32 + q * 8];
#pragma unroll
    for (int j = 0; j < FN; j++)
#pragma unroll
      for (int h = 0; h < 2; h++)
        bfr[j][h] = *(const bf16x8*)
            &Bs[cur * TN * GBK + (wn + j * 16 + ln) * GBK + h * 32 + q * 8];
#pragma unroll
    for (int i = 0; i < FM; i++)
#pragma unroll
      for (int j = 0; j < FN; j++) {
        acc[i][j] = __builtin_amdgcn_mfma_f32_16x16x32_bf16(
            af[i][0], bfr[j][0], acc[i][j], 0, 0, 0);
        acc[i][j] = __builtin_amdgcn_mfma_f32_16x16x32_bf16(
            af[i][1], bfr[j][1], acc[i][j], 0, 0, 0);
      }
    __builtin_amdgcn_s_barrier();        // all waves done reading cur
    __builtin_amdgcn_sched_barrier(0);   // no stage sunk above this barrier
    if (t + 2 < NK) stage(cur, (t + 2) * GBK);
  }

  if constexpr (CT == 1) {
    // Coalesced transposed store via LDS bounce (TM=TN=128 only).
    float (*T)[68] = (float(*)[68])smem;   // [64][68] = 17.4KB, fits As region
#pragma unroll
    for (int ch = 0; ch < 2; ch++) {
      __syncthreads();
      if ((wid & 1) == ch) {
#pragma unroll
        for (int i = 0; i < FM; i++)
#pragma unroll
          for (int j = 0; j < FN; j++)
            *(f32x4*)&T[j * 16 + ln][wm + i * 16 + q * 4] = acc[i][j];
      }
      __syncthreads();
#pragma unroll
      for (int it = 0; it < 8; it++) {
        const int idx = tid + it * 256;
        const int row = idx >> 5, off = (idx & 31) * 4;
        *(f32x4*)&C[(size_t)(nBase + ch * 64 + row) * ldc + mBase + off] =
            *(const f32x4*)&T[row][off];
      }
    }
  } else {
#pragma unroll
    for (int i = 0; i < FM; i++) {
      const int m0 = mBase + wm + i * 16 + q * 4;
#pragma unroll
      for (int j = 0; j < FN; j++) {
        const int n = nBase + wn + j * 16 + ln;
#pragma unroll
        for (int r = 0; r < 4; r++) {
          float v = acc[i][j][r];
          if (MODE == 2) v += aux[(size_t)(m0 + r) * ldc + n];
          C[(size_t)(m0 + r) * ldc + n] = v;
        }
      }
    }
  }
}

// ---------------------------------------------------------------------------
// Fused prep: x cast (blocks 0..2047) + W_in/W_x/W_out transpose-casts.
// ---------------------------------------------------------------------------
__launch_bounds__(256)
__global__ void prep(const float* __restrict__ x, bf16_t* __restrict__ x_b,
                     const float* __restrict__ W_in, bf16_t* __restrict__ W_inT_b,
                     const float* __restrict__ W_x, bf16_t* __restrict__ W_xT_b,
                     const float* __restrict__ W_out, bf16_t* __restrict__ W_outT_b) {
  __shared__ float T[64][65];
  const int blk = blockIdx.x;
  const int t = threadIdx.x;

  if (blk < 2048) {                       // cast x -> x_b (bf16)
    const int i = blk * 256 + t;
    const float4 v = ((const float4*)x)[i];
    bf16x4 o = {(bf16_t)v.x, (bf16_t)v.y, (bf16_t)v.z, (bf16_t)v.w};
    ((bf16x4*)x_b)[i] = o;
    return;
  }
  const float* in;
  bf16_t* out;
  int R, C, bx, by;
  if (blk < 2304) {                       // W_in: [512][2048] -> T
    const int k = blk - 2048;
    in = W_in; out = W_inT_b; R = DD; C = DXZ; bx = k & 31; by = k >> 5;
  } else if (blk < 2320) {                // W_x: [1024][64] -> T
    const int k = blk - 2304;
    in = W_x; out = W_xT_b; R = DIN; C = NDBL; bx = 0; by = k;
  } else {                                // W_out: [1024][512] -> T
    const int k = blk - 2320;
    in = W_out; out = W_outT_b; R = DIN; C = DD; bx = k & 7; by = k >> 3;
  }
  const int rB = by * 64, cB = bx * 64;
  {
    const int r = t >> 4, c4 = (t & 15) * 4;
#pragma unroll
    for (int i = 0; i < 4; i++) {
      const float4 v = *(const float4*)&in[(size_t)(rB + r + i * 16) * C + cB + c4];
      T[r + i * 16][c4] = v.x;
      T[r + i * 16][c4 + 1] = v.y;
      T[r + i * 16][c4 + 2] = v.z;
      T[r + i * 16][c4 + 3] = v.w;
    }
  }
  __syncthreads();
  {
    const int c = t >> 2;
#pragma unroll
    for (int i = 0; i < 4; i++) {
      const int r0 = (t & 3) * 16 + i * 4;
      bf16x4 o = {(bf16_t)T[r0][c], (bf16_t)T[r0 + 1][c],
                  (bf16_t)T[r0 + 2][c], (bf16_t)T[r0 + 3][c]};
      *(bf16x4*)&out[(size_t)(cB + c) * R + rB + r0] = o;
    }
  }
}

// ---------------------------------------------------------------------------
// bf16 tiled transpose: in bf16 [R][C] -> out bf16 [C][R]. 64x64 tiles.
// ---------------------------------------------------------------------------
__launch_bounds__(256)
__global__ void transpose_b16(const bf16_t* __restrict__ in, bf16_t* __restrict__ out,
                              int R, int C) {
  __shared__ bf16_t T[64][72];
  const int t = threadIdx.x;
  const int rB = blockIdx.y * 64, cB = blockIdx.x * 64;
  const int r = t >> 2, c16 = (t & 3) * 16;
#pragma unroll
  for (int i = 0; i < 2; i++) {
    const bf16x8 v = *(const bf16x8*)&in[(size_t)(rB + r) * C + cB + c16 + i * 8];
#pragma unroll
    for (int k = 0; k < 8; k++) T[c16 + i * 8 + k][r] = v[k];
  }
  __syncthreads();
#pragma unroll
  for (int i = 0; i < 2; i++) {
    const int cc = (t & 3) * 16 + i * 8;
    bf16x8 v;
#pragma unroll
    for (int k = 0; k < 8; k++) v[k] = T[r][cc + k];
    *(bf16x8*)&out[(size_t)(cB + r) * R + rB + cc] = v;
  }
}

// ---------------------------------------------------------------------------
// fp32 tiled GEMM (GEMM4 only): 64x64 tile, BK=16.
// MODE 1: softplus(acc+bias[n]); CT=1: transposed store via LDS bounce.
// ---------------------------------------------------------------------------
template <int MODE, int AT, int CT>
__launch_bounds__(256)
__global__ void gemm_tiled(const float* __restrict__ A, int lda,
                           const float* __restrict__ B, int ldb,
                           float* __restrict__ C, int ldc,
                           int M, int N, int K,
                           const float* __restrict__ aux) {
  __shared__ float As[16][68];
  __shared__ float Bs[16][68];

  const int tid = threadIdx.x;
  const int tx = tid & 15, ty = tid >> 4;
  const int mBase = blockIdx.y * 64;
  const int nBase = blockIdx.x * 64;

  float acc[4][4] = {};

  for (int k0 = 0; k0 < K; k0 += 16) {
#pragma unroll
    for (int i = 0; i < 4; i++) {
      int idx = tid + i * 256;
      if (AT == 0) {
        int m = idx >> 4, kk = idx & 15;
        As[kk][m] = A[(size_t)(mBase + m) * lda + k0 + kk];
      } else {
        int kk = idx >> 6, m = idx & 63;
        As[kk][m] = A[(size_t)(k0 + kk) * lda + mBase + m];
      }
    }
#pragma unroll
    for (int i = 0; i < 4; i++) {
      int idx = tid + i * 256;
      int kk = idx >> 6, n = idx & 63;
      Bs[kk][n] = B[(size_t)(k0 + kk) * ldb + nBase + n];
    }
    __syncthreads();
#pragma unroll
    for (int kk = 0; kk < 16; kk++) {
      const float4 a4 = *reinterpret_cast<const float4*>(&As[kk][ty * 4]);
      const float4 b4 = *reinterpret_cast<const float4*>(&Bs[kk][tx * 4]);
      const float a[4] = {a4.x, a4.y, a4.z, a4.w};
      const float b[4] = {b4.x, b4.y, b4.z, b4.w};
#pragma unroll
      for (int i = 0; i < 4; i++)
#pragma unroll
        for (int j = 0; j < 4; j++) acc[i][j] = fmaf(a[i], b[j], acc[i][j]);
    }
    __syncthreads();
  }

  if (CT == 0) {
#pragma unroll
    for (int i = 0; i < 4; i++) {
      const int m = mBase + ty * 4 + i;
      const int n0 = nBase + tx * 4;
      float v[4];
#pragma unroll
      for (int j = 0; j < 4; j++) {
        float x = acc[i][j];
        if (MODE == 1) {
          x += aux[n0 + j];
          x = (x > 20.f) ? x
              : 0.69314718f * __builtin_amdgcn_logf(
                    1.f + __builtin_amdgcn_exp2f(x * 1.44269504f));
        }
        v[j] = x;
      }
      *reinterpret_cast<float4*>(&C[(size_t)m * ldc + n0]) =
          make_float4(v[0], v[1], v[2], v[3]);
    }
  } else {
    // Transposed store via LDS bounce: rows n, 256B contiguous m-segments.
    __shared__ float T3[64][68];
#pragma unroll
    for (int i = 0; i < 4; i++)
#pragma unroll
      for (int j = 0; j < 4; j++) {
        float x = acc[i][j];
        if (MODE == 1) {
          x += aux[nBase + tx * 4 + j];
          x = (x > 20.f) ? x
              : 0.69314718f * __builtin_amdgcn_logf(
                    1.f + __builtin_amdgcn_exp2f(x * 1.44269504f));
        }
        T3[tx * 4 + j][ty * 4 + i] = x;
      }
    __syncthreads();
#pragma unroll
    for (int it = 0; it < 4; it++) {
      const int idx = tid + it * 256;
      const int row = idx >> 4, off = (idx & 15) * 4;
      *(float4*)&C[(size_t)(nBase + row) * ldc + mBase + off] =
          *(const float4*)&T3[row][off];
    }
  }
}

// ---------------------------------------------------------------------------
// Fused depthwise causal conv (k=4) + bias + SiLU + transposed bf16 output.
// ---------------------------------------------------------------------------
__launch_bounds__(256)
__global__ void conv_silu_T2(const float* __restrict__ xzT,
                             const float* __restrict__ conv_w,
                             const float* __restrict__ conv_b,
                             float* __restrict__ uT,
                             bf16_t* __restrict__ u_b) {
  __shared__ bf16_t T[64][72];   // [ml_local][d_local], pad 72
  const int t = threadIdx.x;
  const int d0 = blockIdx.y * 64, ml0 = blockIdx.x * 64;
  const int dd = t >> 2;               // 0..63
  const int m4 = (t & 3) * 16;         // 0,16,32,48
  const int d = d0 + dd;
  const float* row = xzT + (size_t)d * ML + ml0 + m4;
  float* orow = uT + (size_t)d * ML + ml0 + m4;
  const float w0 = conv_w[d * 4 + 0], w1 = conv_w[d * 4 + 1];
  const float w2 = conv_w[d * 4 + 2], w3 = conv_w[d * 4 + 3];
  const float bias = conv_b[d];
  const int l0 = (ml0 + m4) & (LL - 1);
  float4 Av = make_float4(0.f, 0.f, 0.f, 0.f);
  if (l0 != 0) Av = *(const float4*)(row - 4);
#pragma unroll
  for (int j = 0; j < 4; j++) {
    const float4 Bv = *(const float4*)(row + j * 4);
    float o0 = bias + w0 * Av.y + w1 * Av.z + w2 * Av.w + w3 * Bv.x;
    float o1 = bias + w0 * Av.z + w1 * Av.w + w2 * Bv.x + w3 * Bv.y;
    float o2 = bias + w0 * Av.w + w1 * Bv.x + w2 * Bv.y + w3 * Bv.z;
    float o3 = bias + w0 * Bv.x + w1 * Bv.y + w2 * Bv.z + w3 * Bv.w;
    o0 = fast_silu(o0); o1 = fast_silu(o1);
    o2 = fast_silu(o2); o3 = fast_silu(o3);
    *(float4*)(orow + j * 4) = make_float4(o0, o1, o2, o3);
    T[m4 + j * 4 + 0][dd] = (bf16_t)o0;
    T[m4 + j * 4 + 1][dd] = (bf16_t)o1;
    T[m4 + j * 4 + 2][dd] = (bf16_t)o2;
    T[m4 + j * 4 + 3][dd] = (bf16_t)o3;
    Av = Bv;
  }
  __syncthreads();
  const int r = t >> 2;
#pragma unroll
  for (int i = 0; i < 2; i++) {
    const int cc = (t & 3) * 16 + i * 8;
    bf16x8 v;
#pragma unroll
    for (int k = 0; k < 8; k++) v[k] = T[r][cc + k];
    *(bf16x8*)&u_b[(size_t)(ml0 + r) * DIN + d0 + cc] = v;
  }
}

// ---------------------------------------------------------------------------
// Fused chunked selective scan v6f (proven 51.3us, v20): CP=34, lb(256,4),
// bf16 y epilogue into yT_b overlay.
// ---------------------------------------------------------------------------
__launch_bounds__(256, 4)
__global__ void scan_fused6f(const float* __restrict__ dtT,
                             const float* __restrict__ uT,
                             const float* __restrict__ xzT,
                             bf16_t* __restrict__ yT_b,
                             const float* __restrict__ xdbl,
                             const float* __restrict__ A_log,
                             const float* __restrict__ D_param) {
  __shared__ float dt_s[NCH3 * CP4];
  __shared__ float u_s[NCH3 * CP4];     // holds u, then y' after phase 3
  __shared__ float Pc[NCH3][PHS];       // decay products, then Hin in place
  __shared__ float Hc[NCH3][PHS];

  const int tid = threadIdx.x;
  const int c = blockIdx.x;
  const int b = c >> 10, d = c & (DIN - 1);
  const size_t rowoff = (size_t)d * ML + (size_t)b * LL;
  const float* dtrow = dtT + rowoff;
  const float* urow  = uT + rowoff;
  const float* zrow  = xzT + (size_t)(DIN + d) * ML + (size_t)b * LL;
  bf16_t* yrow = yT_b + rowoff;

  // Stage dt,u rows (2048 floats each), coalesced float4: 2 per thread.
#pragma unroll
  for (int i = 0; i < 2; i++) {
    const int idx = (tid + i * 256) * 4;
    const int la = (idx >> 5) * CP4 + (idx & 31);
    *(float4*)&dt_s[la] = *(const float4*)&dtrow[idx];
    *(float4*)&u_s[la]  = *(const float4*)&urow[idx];
  }

  const int ch = tid >> 2, q = tid & 3;
  const int s0 = q * 4;
  float Al2[4];
#pragma unroll
  for (int k = 0; k < 4; k++)
    Al2[k] = -expf(A_log[d * DSTATE + s0 + k]) * 1.44269504f;
  const float* dp = dt_s + ch * CP4;
  float* up = u_s + ch * CP4;
  const float* BC = xdbl + ((size_t)b * LL + (size_t)ch * LC3) * NDBL + DTRANK + s0;
  __syncthreads();

  // Phase 1: local scan (h0=0) -> end-state Hc and decay product Pc.
  {
    float h0 = 0.f, h1 = 0.f, h2 = 0.f, h3 = 0.f, sdt = 0.f;
    float4 Bcur[4];
#pragma unroll
    for (int i = 0; i < 4; i++)
      Bcur[i] = *(const float4*)(BC + (size_t)i * NDBL);
    for (int g = 0; g < 8; g++) {
      float4 Bnxt[4];
      // prefetch next group (g=7 reads rows past the chunk: in-ws, unused)
#pragma unroll
      for (int i = 0; i < 4; i++)
        Bnxt[i] = *(const float4*)(BC + (size_t)((g + 1) * 4 + i) * NDBL);
#pragma unroll
      for (int i = 0; i < 4; i++) {
        const int l = g * 4 + i;
        const float dtv = dp[l];
        const float dtu = dtv * up[l];
        sdt += dtv;
        const float e0 = __builtin_amdgcn_exp2f(dtv * Al2[0]);
        const float e1 = __builtin_amdgcn_exp2f(dtv * Al2[1]);
        const float e2 = __builtin_amdgcn_exp2f(dtv * Al2[2]);
        const float e3 = __builtin_amdgcn_exp2f(dtv * Al2[3]);
        h0 = fmaf(h0, e0, dtu * Bcur[i].x);
        h1 = fmaf(h1, e1, dtu * Bcur[i].y);
        h2 = fmaf(h2, e2, dtu * Bcur[i].z);
        h3 = fmaf(h3, e3, dtu * Bcur[i].w);
      }
#pragma unroll
      for (int i = 0; i < 4; i++) Bcur[i] = Bnxt[i];
    }
    Pc[ch][s0 + 0] = __builtin_amdgcn_exp2f(Al2[0] * sdt);
    Pc[ch][s0 + 1] = __builtin_amdgcn_exp2f(Al2[1] * sdt);
    Pc[ch][s0 + 2] = __builtin_amdgcn_exp2f(Al2[2] * sdt);
    Pc[ch][s0 + 3] = __builtin_amdgcn_exp2f(Al2[3] * sdt);
    Hc[ch][s0 + 0] = h0;
    Hc[ch][s0 + 1] = h1;
    Hc[ch][s0 + 2] = h2;
    Hc[ch][s0 + 3] = h3;
  }
  __syncthreads();

  // Phase 2: serial combine over 64 chunks; Hin overwrites Pc in place.
  if (tid < DSTATE) {
    float h = 0.f;
#pragma unroll
    for (int k = 0; k < NCH3; k++) {
      const float Pv = Pc[k][tid], Hv = Hc[k][tid];
      Pc[k][tid] = h;                 // Hin for chunk k
      h = fmaf(h, Pv, Hv);
    }
  }
  __syncthreads();

  // Phase 3: re-scan from Hin; write pre-gate y' into u_s (slot l is dead
  // after its same-iteration read — wave lanes are synchronous).
  {
    const float Dp = D_param[d];
    float h0 = Pc[ch][s0], h1 = Pc[ch][s0 + 1];
    float h2 = Pc[ch][s0 + 2], h3 = Pc[ch][s0 + 3];
    float4 Bcur[4], Ccur[4];
#pragma unroll
    for (int i = 0; i < 4; i++) {
      Bcur[i] = *(const float4*)(BC + (size_t)i * NDBL);
      Ccur[i] = *(const float4*)(BC + (size_t)i * NDBL + DSTATE);
    }
    for (int g = 0; g < 8; g++) {
      float4 Bnxt[4], Cnxt[4];
#pragma unroll
      for (int i = 0; i < 4; i++) {
        Bnxt[i] = *(const float4*)(BC + (size_t)((g + 1) * 4 + i) * NDBL);
        Cnxt[i] = *(const float4*)(BC + (size_t)((g + 1) * 4 + i) * NDBL + DSTATE);
      }
#pragma unroll
      for (int i = 0; i < 4; i++) {
        const int l = g * 4 + i;
        const float dtv = dp[l];
        const float uv = up[l];
        const float dtu = dtv * uv;
        const float e0 = __builtin_amdgcn_exp2f(dtv * Al2[0]);
        const float e1 = __builtin_amdgcn_exp2f(dtv * Al2[1]);
        const float e2 = __builtin_amdgcn_exp2f(dtv * Al2[2]);
        const float e3 = __builtin_amdgcn_exp2f(dtv * Al2[3]);
        h0 = fmaf(h0, e0, dtu * Bcur[i].x);
        h1 = fmaf(h1, e1, dtu * Bcur[i].y);
        h2 = fmaf(h2, e2, dtu * Bcur[i].z);
        h3 = fmaf(h3, e3, dtu * Bcur[i].w);
        float p = fmaf(h0, Ccur[i].x,
                  fmaf(h1, Ccur[i].y, fmaf(h2, Ccur[i].z, h3 * Ccur[i].w)));
        p += __int_as_float(__builtin_amdgcn_ds_swizzle(__float_as_int(p), 0x041F));
        p += __int_as_float(__builtin_amdgcn_ds_swizzle(__float_as_int(p), 0x081F));
        if (q == (l & 3)) up[l] = fmaf(uv, Dp, p);   // y' into dead u slot
      }
#pragma unroll
      for (int i = 0; i < 4; i++) { Bcur[i] = Bnxt[i]; Ccur[i] = Cnxt[i]; }
    }
  }
  __syncthreads();

  // Epilogue: coalesced gated bf16 write  y = bf16(y' * silu(z)).
#pragma unroll
  for (int i = 0; i < 2; i++) {
    const int idx = (tid + i * 256) * 4;
    const int la = (idx >> 5) * CP4 + (idx & 31);
    const float4 y4 = *(const float4*)&u_s[la];
    const float4 z4 = *(const float4*)&zrow[idx];
    bf16x4 o = {(bf16_t)(y4.x * fast_silu(z4.x)),
                (bf16_t)(y4.y * fast_silu(z4.y)),
                (bf16_t)(y4.z * fast_silu(z4.z)),
                (bf16_t)(y4.w * fast_silu(z4.w))};
    *(bf16x4*)&yrow[idx] = o;
  }
}

// ---------------------------------------------------------------------------
extern "C" void kernel_launch(void* const* d_in, const int* in_sizes, int n_in,
                              void* d_out, int out_size, void* d_ws, size_t ws_size,
                              hipStream_t stream) {
  const float* x      = (const float*)d_in[0];
  const float* W_in   = (const float*)d_in[1];
  const float* conv_w = (const float*)d_in[2];
  const float* conv_b = (const float*)d_in[3];
  const float* W_x    = (const float*)d_in[4];
  const float* W_dt   = (const float*)d_in[5];
  const float* b_dt   = (const float*)d_in[6];
  const float* A_log  = (const float*)d_in[7];
  const float* D_par  = (const float*)d_in[8];
  const float* W_out  = (const float*)d_in[9];
  float* out = (float*)d_out;

  char* ws = (char*)d_ws;
  float* xzT   = (float*)(ws);                                  // [2048][4096] 32MB
  bf16_t* yT_b = (bf16_t*)(ws);             // overlay: first 8MB of xzT (rows
                                            // 0..1023 are dead by scan time)
  float* uT    = (float*)(ws + (size_t)ML * DXZ * 4);           // [1024][4096] 16MB
  float* x_dbl = (float*)(ws + (size_t)ML * (DXZ + DIN) * 4);   // [4096][64]   1MB
  char* dtT_b  = ws + (size_t)ML * (DXZ + DIN + NDBL) * 4;
  float* dtT   = (float*)dtT_b;                                 // [1024][4096] 16MB
  bf16_t* u_b  = (bf16_t*)dtT_b;            // overlay: dead before GEMM4 writes dtT (8MB)
  bf16_t* y_b  = (bf16_t*)(dtT_b + (size_t)ML * DIN * 2);       // overlay: after scan (8MB)
  char* extra  = ws + (size_t)ML * (DXZ + DIN + NDBL + DIN) * 4;
  bf16_t* x_b      = (bf16_t*)(extra);                          // [4096][512]  4MB
  bf16_t* W_inT_b  = (bf16_t*)(extra + (size_t)ML * DD * 2);    // [2048][512]  2MB
  bf16_t* W_outT_b = (bf16_t*)(extra + (size_t)ML * DD * 2 + (size_t)DXZ * DD * 2); // [512][1024] 1MB
  bf16_t* W_xT_b   = (bf16_t*)(extra + (size_t)ML * DD * 2 + (size_t)DXZ * DD * 2
                               + (size_t)DD * DIN * 2);         // [64][1024] 128KB

  // 0) fused prep: x cast + all weight transposes (one launch)
  prep<<<2448, 256, 0, stream>>>(x, x_b, W_in, W_inT_b, W_x, W_xT_b,
                                 W_out, W_outT_b);

  // 1) xzT = (x @ W_in)^T  via bf16 MFMA, coalesced transposed epilogue
  gemm_mfma<128, 128, 0, 1><<<512, 256, 0, stream>>>(
      x_b, W_inT_b, xzT, ML, ML, DXZ, DD, 16, nullptr);

  // 2) uT = silu(causal_conv4(xzT rows 0..1023) + conv_b); also emits
  //    u_b = bf16 transpose (fused)
  conv_silu_T2<<<dim3(ML / 64, DIN / 64), 256, 0, stream>>>(
      xzT, conv_w, conv_b, uT, u_b);

  // 3) x_dbl = u @ W_x  via bf16 MFMA  (4096x1024)@(1024x64)  (64 wgs, gx=1)
  gemm_mfma<64, 64, 0, 0><<<64, 256, 0, stream>>>(
      u_b, W_xT_b, x_dbl, NDBL, ML, NDBL, DIN, 1, nullptr);

  // 4) dtT = softplus(x_dbl[:, :32] @ W_dt + b_dt)^T  (fp32, K=32),
  //    coalesced transposed store via LDS bounce
  gemm_tiled<1, 0, 1><<<dim3(DIN / 64, ML / 64), 256, 0, stream>>>(
      x_dbl, NDBL, W_dt, DIN, dtT, ML, ML, DIN, DTRANK, b_dt);

  // 5) fused chunked scan + gated bf16 epilogue -> yT_b (overlay on dead
  //    xzT rows 0..1023; z rows 1024..2047 untouched)
  scan_fused6f<<<BB * DIN, 256, 0, stream>>>(dtT, uT, xzT, yT_b, x_dbl,
                                             A_log, D_par);

  // 5b) y_b = transpose(yT_b) -> bf16 [4096][1024]
  transpose_b16<<<dim3(ML / 64, DIN / 64), 256, 0, stream>>>(yT_b, y_b, DIN, ML);

  // 6) out = x + y @ W_out  via bf16 MFMA, residual fused (256 wgs, gx=8)
  gemm_mfma<128, 64, 2, 0><<<256, 256, 0, stream>>>(
      y_b, W_outT_b, out, DD, ML, DD, DIN, 8, x);
}